// Round 3
// baseline (112.943 us; speedup 1.0000x reference)
//
#include <hip/hip_runtime.h>
#include <math.h>

#define BB 16
#define TT 2048
#define CC 32
#define HH 4
#define DD 8

#define KBS 2056      // per-head K buffer stride in halves (256*8 + 8 pad)
#define VRS 264       // V^T row stride in halves (256 + 8 pad)
#define VBS (9 * VRS) // per-head V buffer halves
#define ZP 33         // LDS row stride in floats

typedef __fp16 h2  __attribute__((ext_vector_type(2)));
typedef __fp16 h8  __attribute__((ext_vector_type(8)));
typedef float  fx16 __attribute__((ext_vector_type(16)));
typedef int    i4v __attribute__((ext_vector_type(4)));
typedef int    i2v __attribute__((ext_vector_type(2)));

__device__ __forceinline__ h2 pkh(float a, float b) {
#if __has_builtin(__builtin_amdgcn_cvt_pkrtz)
    return __builtin_amdgcn_cvt_pkrtz(a, b);
#else
    h2 r; r.x = (__fp16)a; r.y = (__fp16)b; return r;
#endif
}

__device__ __forceinline__ float fexp2(float x) {
#if __has_builtin(__builtin_amdgcn_exp2f)
    return __builtin_amdgcn_exp2f(x);
#else
    return exp2f(x);
#endif
}

__device__ __forceinline__ int h2bits(h2 v) { return __builtin_bit_cast(int, v); }

// S (QK^T C-layout) -> exp -> two B-operand P fragments (verified R7-R17).
// Cross-half exchange via v_permlane32_swap (VALU, no DS latency).
__device__ __forceinline__ void makeP(const fx16& S, bool last, int thr, int hi, h8* P) {
    float pe[16];
    #pragma unroll
    for (int r = 0; r < 16; r++) {
        const int ko = (r & 3) + 8 * (r >> 2);
        float sv = S[r];
        if (last) sv = (ko <= thr) ? sv : -INFINITY;
        pe[r] = fexp2(sv);
    }
    int Hh[8];
    #pragma unroll
    for (int i = 0; i < 8; i++) Hh[i] = h2bits(pkh(pe[2*i], pe[2*i+1]));
#if __has_builtin(__builtin_amdgcn_permlane32_swap)
    #pragma unroll
    for (int s = 0; s < 2; s++) {
        const int b0 = 4 * s;
        auto ra = __builtin_amdgcn_permlane32_swap(Hh[b0+0], Hh[b0+2], false, false);
        auto rb = __builtin_amdgcn_permlane32_swap(Hh[b0+1], Hh[b0+3], false, false);
        i2v pa = __builtin_bit_cast(i2v, ra);
        i2v pb = __builtin_bit_cast(i2v, rb);
        i4v f;
        f.x = pa.x; f.y = pb.x; f.z = pa.y; f.w = pb.y;
        P[s] = __builtin_bit_cast(h8, f);
    }
#else
    #pragma unroll
    for (int s = 0; s < 2; s++) {
        const int b0 = 4 * s;
        int own0 = hi ? Hh[b0+2] : Hh[b0+0];
        int own1 = hi ? Hh[b0+3] : Hh[b0+1];
        int snd0 = hi ? Hh[b0+0] : Hh[b0+2];
        int snd1 = hi ? Hh[b0+1] : Hh[b0+3];
        int rcv0 = __shfl_xor(snd0, 32);
        int rcv1 = __shfl_xor(snd1, 32);
        i4v f;
        f.x = hi ? rcv0 : own0;
        f.y = hi ? rcv1 : own1;
        f.z = hi ? own0 : rcv0;
        f.w = hi ? own1 : rcv1;
        P[s] = __builtin_bit_cast(h8, f);
    }
#endif
}

// ---------------- Kernel 1: QKV projection (unchanged from R17) ----------------
__global__ __launch_bounds__(256) void qkv_kernel(
    const float* __restrict__ x,
    const float* __restrict__ Wq, const float* __restrict__ bq,
    const float* __restrict__ Wk, const float* __restrict__ bk,
    const float* __restrict__ Wv, const float* __restrict__ bv,
    __fp16* __restrict__ Qo, __fp16* __restrict__ Ko, __fp16* __restrict__ Vo)
{
    __shared__ float Xs[256 * ZP];
    const int tid = threadIdx.x;
    const int h = blockIdx.y;
    const int row0 = blockIdx.x * 256;

    {   // coalesced stage of 256 x-rows (32 KB), padded stride 33
        const float4* xg = (const float4*)(x + (size_t)row0 * CC);
        #pragma unroll
        for (int i = 0; i < 8; i++) {
            const int idx = tid + 256 * i;
            float4 f = xg[idx];
            const int w = idx * 4;
            float* d = &Xs[(w >> 5) * ZP + (w & 31)];
            d[0] = f.x; d[1] = f.y; d[2] = f.z; d[3] = f.w;
        }
    }
    __syncthreads();

    const int row = row0 + tid;
    const int b = row >> 11, t = row & 2047;
    const int bh = b * HH + h;

    float xr[CC];
    #pragma unroll
    for (int c = 0; c < CC; c++) xr[c] = Xs[tid * ZP + c];

    // ---- Q ----
    {
        float o[DD];
        #pragma unroll
        for (int d = 0; d < DD; d++) {
            const int dd = h * DD + d;
            float acc = bq[dd];
            #pragma unroll
            for (int c = 0; c < CC; c++) acc += xr[c] * Wq[dd * CC + c];
            o[d] = acc;
        }
        const float qs = 0.3535533905932738f * 1.4426950408889634f;
        i4v qw;
        qw.x = h2bits(pkh(o[0]*qs, o[1]*qs)); qw.y = h2bits(pkh(o[2]*qs, o[3]*qs));
        qw.z = h2bits(pkh(o[4]*qs, o[5]*qs)); qw.w = h2bits(pkh(o[6]*qs, o[7]*qs));
        *(i4v*)(Qo + ((size_t)bh * TT + t) * DD) = qw;
    }
    // ---- K ----
    {
        float o[DD];
        #pragma unroll
        for (int d = 0; d < DD; d++) {
            const int dd = h * DD + d;
            float acc = bk[dd];
            #pragma unroll
            for (int c = 0; c < CC; c++) acc += xr[c] * Wk[dd * CC + c];
            o[d] = acc;
        }
        i4v kw;
        kw.x = h2bits(pkh(o[0], o[1])); kw.y = h2bits(pkh(o[2], o[3]));
        kw.z = h2bits(pkh(o[4], o[5])); kw.w = h2bits(pkh(o[6], o[7]));
        *(i4v*)(Ko + ((size_t)bh * TT + t) * DD) = kw;
    }
    // ---- V (transposed store + ones row for the l trick) ----
    {
        float o[DD];
        #pragma unroll
        for (int d = 0; d < DD; d++) {
            const int dd = h * DD + d;
            float acc = bv[dd];
            #pragma unroll
            for (int c = 0; c < CC; c++) acc += xr[c] * Wv[dd * CC + c];
            o[d] = acc;
        }
        __fp16* vt = Vo + (size_t)bh * 9 * TT + t;
        #pragma unroll
        for (int d = 0; d < DD; d++) vt[d * TT] = (__fp16)o[d];
        vt[8 * TT] = (__fp16)1.0f;
    }
}

// ---------------- Kernel 2: fused attention + projection (R18) ---------------
// 8 waves (512 thr): wave w = head (w&3), qsel (w>>2): 0=light qgroup ip,
// 1=heavy qgroup 63-ip. Light+heavy of the same head SHARE one K/V LDS
// buffer; only the heavy wave stages (its key range is a superset of the
// light wave's prefix). This keeps R10's staging volume (R16's regression
// was 1.5x staging duplication) while doubling waves/SIMD to 4 for latency
// hiding. 2 barriers per super-tile. Wave->SIMD round-robin puts {light h,
// heavy h} on one SIMD = 65 tiles/SIMD/block, balanced by construction.
__global__ __launch_bounds__(512, 4) void attn_kernel(
    const __fp16* __restrict__ Qg, const __fp16* __restrict__ Kg,
    const __fp16* __restrict__ Vg,
    const float* __restrict__ Wp, const float* __restrict__ bp,
    float* __restrict__ out)
{
    __shared__ __align__(16) __fp16 KsS[4 * KBS];
    __shared__ __align__(16) __fp16 VtS[4 * VBS];
    __shared__ float zbuf[64 * ZP];

    const int tid  = threadIdx.x;
    const int b    = blockIdx.x & 15;
    const int ip   = blockIdx.x >> 4;       // pair index 0..31
    const int w    = tid >> 6;              // wave 0..7
    const int h    = w & 3;                 // head
    const int qsel = w >> 2;                // 0 = light qgroup, 1 = heavy
    const int lane = tid & 63;
    const int qc   = lane & 31;
    const int hi   = lane >> 5;

    const int bh  = b * HH + h;
    const int qb  = 32 * (qsel ? (63 - ip) : ip);
    const int keys_needed = qb + 32;
    // block-uniform super-tile count = heavy wave's requirement
    const int nstBlk = (32 * (63 - ip) + 32 + 255) >> 8;

    h8 qf;
    {   // B operand: Q^T (pre-scaled); hi half zero (annihilates A garbage)
        h8 qz;
        #pragma unroll
        for (int i = 0; i < 8; i++) qz[i] = (__fp16)0.0f;
        h8 qa = *(const h8*)(Qg + ((size_t)bh * TT + qb + qc) * DD);
        qf = hi ? qz : qa;
    }

    fx16 O, zc;
    #pragma unroll
    for (int i = 0; i < 16; i++) { O[i] = 0.0f; zc[i] = 0.0f; }

    const int vrow = (qc < 9) ? qc : 8;     // rows>=9 -> ones row (l trick)
    const int thr  = qc - 4 * hi;

    const __fp16* kgl = Kg + (size_t)bh * TT * DD;
    const __fp16* vgl = Vg + (size_t)bh * 9 * TT;
    __fp16* kld = KsS + h * KBS;            // shared per head
    __fp16* vld = VtS + h * VBS;
    const __fp16* kb = kld + qc * DD;
    const __fp16* vb = vld + vrow * VRS + 8 * hi;

    i4v kpre[4], vpre[5];
    if (qsel) {   // heavy wave prefetches super-tile 0
        const i4v* ks = (const i4v*)kgl;
        #pragma unroll
        for (int r = 0; r < 4; r++) kpre[r] = ks[lane + 64 * r];
        #pragma unroll
        for (int r = 0; r < 5; r++) {
            int i = lane + 64 * r; if (i > 287) i = 287;
            vpre[r] = *(const i4v*)(vgl + (i >> 5) * TT + (i & 31) * 8);
        }
    }

    for (int sti = 0; sti < nstBlk; sti++) {
        const int st = sti * 256;
        if (qsel) {   // heavy wave commits prefetched tile to shared LDS
            i4v* kd = (i4v*)kld;
            #pragma unroll
            for (int r = 0; r < 4; r++) kd[lane + 64 * r] = kpre[r];
            #pragma unroll
            for (int r = 0; r < 5; r++) {
                const int i = lane + 64 * r;
                if (i < 288) *(i4v*)(vld + (i >> 5) * VRS + (i & 31) * 8) = vpre[r];
            }
            if (sti + 1 < nstBlk) {   // issue next tile's global loads
                const int st2 = st + 256;
                const i4v* ks = (const i4v*)(kgl + (size_t)st2 * DD);
                #pragma unroll
                for (int r = 0; r < 4; r++) kpre[r] = ks[lane + 64 * r];
                #pragma unroll
                for (int r = 0; r < 5; r++) {
                    int i = lane + 64 * r; if (i > 287) i = 287;
                    vpre[r] = *(const i4v*)(vgl + (i >> 5) * TT + st2 + (i & 31) * 8);
                }
            }
        }
        __syncthreads();   // commit visible to both waves of this head

        const int kend = min(st + 256, keys_needed);
        for (int kt = st; kt < kend; kt += 32) {
            h8 kf = *(const h8*)(kb + (kt - st) * DD);
            fx16 S = __builtin_amdgcn_mfma_f32_32x32x16_f16(kf, qf, zc, 0, 0, 0);
            h8 P[2];
            makeP(S, kt == qb, thr, hi, P);
            #pragma unroll
            for (int s = 0; s < 2; s++) {
                h8 vf = *(const h8*)(vb + (kt - st) + 16 * s);
                O = __builtin_amdgcn_mfma_f32_32x32x16_f16(vf, P[s], O, 0, 0, 0);
            }
        }
        __syncthreads();   // all readers done before next commit overwrites
    }

    {   // z -> LDS: O[4] = l (ones-row); regs 0-3 = d0-3 (hi=0) / d4-7 (hi=1)
        const float inv = 1.0f / O[4];
        float* z = &zbuf[(qsel * 32 + qc) * ZP + h * DD + 4 * hi];
        z[0] = O[0]*inv; z[1] = O[1]*inv; z[2] = O[2]*inv; z[3] = O[3]*inv;
    }
    __syncthreads();

    {   // in-block projection: wave = 4-col output segment (uniform Wp -> s_loads)
        const int seg = tid >> 6;           // 0..7 -> cols seg*4..seg*4+3
        const int r = tid & 63;             // rows 0-31 -> qg ip, 32-63 -> qg 63-ip
        float zr[CC];
        #pragma unroll
        for (int c = 0; c < CC; c++) zr[c] = zbuf[r * ZP + c];
        float o[4];
        #pragma unroll
        for (int d = 0; d < 4; d++) {
            const int dd = seg * 4 + d;
            float acc = bp[dd];
            #pragma unroll
            for (int c = 0; c < CC; c++) acc += zr[c] * Wp[dd * CC + c];
            o[d] = acc;
        }
        const int qglob = (r < 32) ? (ip * 32 + r) : ((63 - ip) * 32 + (r - 32));
        float* dst = out + ((size_t)b * TT + qglob) * CC + seg * 4;
        *(float4*)dst = make_float4(o[0], o[1], o[2], o[3]);
    }
}

extern "C" void kernel_launch(void* const* d_in, const int* in_sizes, int n_in,
                              void* d_out, int out_size, void* d_ws, size_t ws_size,
                              hipStream_t stream) {
    const float* x  = (const float*)d_in[0];
    const float* Wq = (const float*)d_in[1];
    const float* bq = (const float*)d_in[2];
    const float* Wk = (const float*)d_in[3];
    const float* bk = (const float*)d_in[4];
    const float* Wv = (const float*)d_in[5];
    const float* bv = (const float*)d_in[6];
    const float* Wp = (const float*)d_in[7];
    const float* bp = (const float*)d_in[8];
    float* out = (float*)d_out;

    const size_t NE = (size_t)BB * HH * TT * DD;   // 1M
    __fp16* Qh = (__fp16*)d_ws;                    // 2 MB (pre-scaled)
    __fp16* Kh = Qh + NE;                          // 2 MB
    __fp16* Vt = Kh + NE;                          // 2.25 MB  [bh][9][T]

    qkv_kernel<<<dim3(BB * TT / 256, HH), 256, 0, stream>>>(x, Wq, bq, Wk, bk, Wv, bv, Qh, Kh, Vt);
    attn_kernel<<<dim3(BB * 32), 512, 0, stream>>>(Qh, Kh, Vt, Wp, bp, out);
}

// Round 4
// 112.623 us; speedup vs baseline: 1.0028x; 1.0028x over previous
//
#include <hip/hip_runtime.h>
#include <math.h>

#define BB 16
#define TT 2048
#define CC 32
#define HH 4
#define DD 8

#define ZP 33         // LDS row stride in floats

typedef __fp16 h2  __attribute__((ext_vector_type(2)));
typedef __fp16 h8  __attribute__((ext_vector_type(8)));
typedef float  fx16 __attribute__((ext_vector_type(16)));
typedef int    i4v __attribute__((ext_vector_type(4)));
typedef int    i2v __attribute__((ext_vector_type(2)));

__device__ __forceinline__ h2 pkh(float a, float b) {
#if __has_builtin(__builtin_amdgcn_cvt_pkrtz)
    return __builtin_amdgcn_cvt_pkrtz(a, b);
#else
    h2 r; r.x = (__fp16)a; r.y = (__fp16)b; return r;
#endif
}

__device__ __forceinline__ float fexp2(float x) {
#if __has_builtin(__builtin_amdgcn_exp2f)
    return __builtin_amdgcn_exp2f(x);
#else
    return exp2f(x);
#endif
}

__device__ __forceinline__ int h2bits(h2 v) { return __builtin_bit_cast(int, v); }

// S (QK^T C-layout) -> exp -> two B-operand P fragments (verified R7-R17).
// Cross-half exchange via v_permlane32_swap (VALU, no DS latency).
__device__ __forceinline__ void makeP(const fx16& S, bool last, int thr, int hi, h8* P) {
    float pe[16];
    #pragma unroll
    for (int r = 0; r < 16; r++) {
        const int ko = (r & 3) + 8 * (r >> 2);
        float sv = S[r];
        if (last) sv = (ko <= thr) ? sv : -INFINITY;
        pe[r] = fexp2(sv);
    }
    int Hh[8];
    #pragma unroll
    for (int i = 0; i < 8; i++) Hh[i] = h2bits(pkh(pe[2*i], pe[2*i+1]));
#if __has_builtin(__builtin_amdgcn_permlane32_swap)
    #pragma unroll
    for (int s = 0; s < 2; s++) {
        const int b0 = 4 * s;
        auto ra = __builtin_amdgcn_permlane32_swap(Hh[b0+0], Hh[b0+2], false, false);
        auto rb = __builtin_amdgcn_permlane32_swap(Hh[b0+1], Hh[b0+3], false, false);
        i2v pa = __builtin_bit_cast(i2v, ra);
        i2v pb = __builtin_bit_cast(i2v, rb);
        i4v f;
        f.x = pa.x; f.y = pb.x; f.z = pa.y; f.w = pb.y;
        P[s] = __builtin_bit_cast(h8, f);
    }
#else
    #pragma unroll
    for (int s = 0; s < 2; s++) {
        const int b0 = 4 * s;
        int own0 = hi ? Hh[b0+2] : Hh[b0+0];
        int own1 = hi ? Hh[b0+3] : Hh[b0+1];
        int snd0 = hi ? Hh[b0+0] : Hh[b0+2];
        int snd1 = hi ? Hh[b0+1] : Hh[b0+3];
        int rcv0 = __shfl_xor(snd0, 32);
        int rcv1 = __shfl_xor(snd1, 32);
        i4v f;
        f.x = hi ? rcv0 : own0;
        f.y = hi ? rcv1 : own1;
        f.z = hi ? own0 : rcv0;
        f.w = hi ? own1 : rcv1;
        P[s] = __builtin_bit_cast(h8, f);
    }
#endif
}

// ---------------- Kernel 1: QKV projection (unchanged from R17) ----------------
__global__ __launch_bounds__(256) void qkv_kernel(
    const float* __restrict__ x,
    const float* __restrict__ Wq, const float* __restrict__ bq,
    const float* __restrict__ Wk, const float* __restrict__ bk,
    const float* __restrict__ Wv, const float* __restrict__ bv,
    __fp16* __restrict__ Qo, __fp16* __restrict__ Ko, __fp16* __restrict__ Vo)
{
    __shared__ float Xs[256 * ZP];
    const int tid = threadIdx.x;
    const int h = blockIdx.y;
    const int row0 = blockIdx.x * 256;

    {   // coalesced stage of 256 x-rows (32 KB), padded stride 33
        const float4* xg = (const float4*)(x + (size_t)row0 * CC);
        #pragma unroll
        for (int i = 0; i < 8; i++) {
            const int idx = tid + 256 * i;
            float4 f = xg[idx];
            const int w = idx * 4;
            float* d = &Xs[(w >> 5) * ZP + (w & 31)];
            d[0] = f.x; d[1] = f.y; d[2] = f.z; d[3] = f.w;
        }
    }
    __syncthreads();

    const int row = row0 + tid;
    const int b = row >> 11, t = row & 2047;
    const int bh = b * HH + h;

    float xr[CC];
    #pragma unroll
    for (int c = 0; c < CC; c++) xr[c] = Xs[tid * ZP + c];

    // ---- Q ----
    {
        float o[DD];
        #pragma unroll
        for (int d = 0; d < DD; d++) {
            const int dd = h * DD + d;
            float acc = bq[dd];
            #pragma unroll
            for (int c = 0; c < CC; c++) acc += xr[c] * Wq[dd * CC + c];
            o[d] = acc;
        }
        const float qs = 0.3535533905932738f * 1.4426950408889634f;
        i4v qw;
        qw.x = h2bits(pkh(o[0]*qs, o[1]*qs)); qw.y = h2bits(pkh(o[2]*qs, o[3]*qs));
        qw.z = h2bits(pkh(o[4]*qs, o[5]*qs)); qw.w = h2bits(pkh(o[6]*qs, o[7]*qs));
        *(i4v*)(Qo + ((size_t)bh * TT + t) * DD) = qw;
    }
    // ---- K ----
    {
        float o[DD];
        #pragma unroll
        for (int d = 0; d < DD; d++) {
            const int dd = h * DD + d;
            float acc = bk[dd];
            #pragma unroll
            for (int c = 0; c < CC; c++) acc += xr[c] * Wk[dd * CC + c];
            o[d] = acc;
        }
        i4v kw;
        kw.x = h2bits(pkh(o[0], o[1])); kw.y = h2bits(pkh(o[2], o[3]));
        kw.z = h2bits(pkh(o[4], o[5])); kw.w = h2bits(pkh(o[6], o[7]));
        *(i4v*)(Ko + ((size_t)bh * TT + t) * DD) = kw;
    }
    // ---- V (transposed store + ones row for the l trick) ----
    {
        float o[DD];
        #pragma unroll
        for (int d = 0; d < DD; d++) {
            const int dd = h * DD + d;
            float acc = bv[dd];
            #pragma unroll
            for (int c = 0; c < CC; c++) acc += xr[c] * Wv[dd * CC + c];
            o[d] = acc;
        }
        __fp16* vt = Vo + (size_t)bh * 9 * TT + t;
        #pragma unroll
        for (int d = 0; d < DD; d++) vt[d * TT] = (__fp16)o[d];
        vt[8 * TT] = (__fp16)1.0f;
    }
}

// ---------------- Kernel 2: fused attention + projection (R19) ---------------
// LDS K/V staging DELETED: K/V are L2-resident (4.25 MB total, ~4 TB/s needed
// << 34.5 TB/s L2) so the global->reg->LDS->reg round-trip bought nothing.
// K/V fragments load straight from global with a depth-1 rolling register
// prefetch. This removes the staging-duplication penalty that killed R16,
// so the wave unit shrinks to ONE qgroup: block = (b, qg) x 4 heads = 4
// EQUAL-length waves (final barrier costless). Grid 1024, big-first (LPT).
// LDS 4.3 KB + VGPR<=128 -> 4 blocks/CU -> 4 waves/SIMD of independent chains.
__global__ __launch_bounds__(256, 4) void attn_kernel(
    const __fp16* __restrict__ Qg, const __fp16* __restrict__ Kg,
    const __fp16* __restrict__ Vg,
    const float* __restrict__ Wp, const float* __restrict__ bp,
    float* __restrict__ out)
{
    __shared__ float zbuf[32 * ZP];

    const int tid  = threadIdx.x;
    const int bx   = blockIdx.x;
    const int b    = bx & 15;
    const int qg   = 63 - (bx >> 4);        // big-first launch order
    const int h    = tid >> 6;              // wave = head
    const int lane = tid & 63;
    const int qc   = lane & 31;
    const int hi   = lane >> 5;

    const int bh  = b * HH + h;
    const int qb  = 32 * qg;
    const int keys_needed = qb + 32;

    h8 qf;
    {   // B operand: Q^T (pre-scaled); hi half zero (annihilates A garbage)
        h8 qz;
        #pragma unroll
        for (int i = 0; i < 8; i++) qz[i] = (__fp16)0.0f;
        h8 qa = *(const h8*)(Qg + ((size_t)bh * TT + qb + qc) * DD);
        qf = hi ? qz : qa;
    }

    fx16 O, zc;
    #pragma unroll
    for (int i = 0; i < 16; i++) { O[i] = 0.0f; zc[i] = 0.0f; }

    const int vrow = (qc < 9) ? qc : 8;     // rows>=9 -> ones row (l trick)
    const int thr  = qc - 4 * hi;

    // per-lane global bases (L2-resident streams)
    const __fp16* kgl = Kg + ((size_t)bh * TT + qc) * DD;      // K row qc, 16B/lane
    const __fp16* vgl = Vg + (size_t)bh * 9 * TT + vrow * TT + 8 * hi;

    // depth-1 rolling register prefetch (no LDS, no barriers, no duplication)
    h8 kf_c  = *(const h8*)(kgl);
    h8 vf0_c = *(const h8*)(vgl);
    h8 vf1_c = *(const h8*)(vgl + 16);

    for (int kt = 0; kt < keys_needed; kt += 32) {
        const int ktn = (kt + 32 < keys_needed) ? kt + 32 : 0;  // clamp: reload t0
        h8 kf_n  = *(const h8*)(kgl + ktn * DD);
        h8 vf0_n = *(const h8*)(vgl + ktn);
        h8 vf1_n = *(const h8*)(vgl + ktn + 16);

        fx16 S = __builtin_amdgcn_mfma_f32_32x32x16_f16(kf_c, qf, zc, 0, 0, 0);
        h8 P[2];
        makeP(S, kt == qb, thr, hi, P);
        O = __builtin_amdgcn_mfma_f32_32x32x16_f16(vf0_c, P[0], O, 0, 0, 0);
        O = __builtin_amdgcn_mfma_f32_32x32x16_f16(vf1_c, P[1], O, 0, 0, 0);

        kf_c = kf_n; vf0_c = vf0_n; vf1_c = vf1_n;
    }

    {   // z -> LDS: O[4] = l (ones-row); regs 0-3 = d0-3 (hi=0) / d4-7 (hi=1)
        const float inv = 1.0f / O[4];
        float* z = &zbuf[qc * ZP + h * DD + 4 * hi];
        z[0] = O[0]*inv; z[1] = O[1]*inv; z[2] = O[2]*inv; z[3] = O[3]*inv;
    }
    __syncthreads();   // all 4 waves equal-length -> negligible wait

    {   // in-block projection: 32 rows x 32 cols; thread = (row, 4-col seg)
        const int seg = tid >> 5;           // 0..7 -> cols seg*4..seg*4+3
        const int r   = tid & 31;
        float zr[CC];
        #pragma unroll
        for (int c = 0; c < CC; c++) zr[c] = zbuf[r * ZP + c];
        float o[4];
        #pragma unroll
        for (int d = 0; d < 4; d++) {
            const int dd = seg * 4 + d;
            float acc = bp[dd];
            #pragma unroll
            for (int c = 0; c < CC; c++) acc += zr[c] * Wp[dd * CC + c];
            o[d] = acc;
        }
        float* dst = out + ((size_t)b * TT + qb + r) * CC + seg * 4;
        *(float4*)dst = make_float4(o[0], o[1], o[2], o[3]);
    }
}

extern "C" void kernel_launch(void* const* d_in, const int* in_sizes, int n_in,
                              void* d_out, int out_size, void* d_ws, size_t ws_size,
                              hipStream_t stream) {
    const float* x  = (const float*)d_in[0];
    const float* Wq = (const float*)d_in[1];
    const float* bq = (const float*)d_in[2];
    const float* Wk = (const float*)d_in[3];
    const float* bk = (const float*)d_in[4];
    const float* Wv = (const float*)d_in[5];
    const float* bv = (const float*)d_in[6];
    const float* Wp = (const float*)d_in[7];
    const float* bp = (const float*)d_in[8];
    float* out = (float*)d_out;

    const size_t NE = (size_t)BB * HH * TT * DD;   // 1M
    __fp16* Qh = (__fp16*)d_ws;                    // 2 MB (pre-scaled)
    __fp16* Kh = Qh + NE;                          // 2 MB
    __fp16* Vt = Kh + NE;                          // 2.25 MB  [bh][9][T]

    qkv_kernel<<<dim3(BB * TT / 256, HH), 256, 0, stream>>>(x, Wq, bq, Wk, bk, Wv, bv, Qh, Kh, Vt);
    attn_kernel<<<dim3(BB * 64), 256, 0, stream>>>(Qh, Kh, Vt, Wp, bp, out);
}

// Round 6
// 105.956 us; speedup vs baseline: 1.0659x; 1.0629x over previous
//
#include <hip/hip_runtime.h>
#include <math.h>

#define BB 16
#define TT 2048
#define CC 32
#define HH 4
#define DD 8

#define KBS 2056      // per-wave K buffer stride in halves (256*8 + 8 pad)
#define VRS 264       // V^T row stride in halves (256 + 8 pad)
#define VBS (9 * VRS) // per-wave V buffer halves
#define ZP 33         // LDS row stride in floats

typedef __fp16 h2  __attribute__((ext_vector_type(2)));
typedef __fp16 h8  __attribute__((ext_vector_type(8)));
typedef float  fx16 __attribute__((ext_vector_type(16)));
typedef int    i4v __attribute__((ext_vector_type(4)));
typedef int    i2v __attribute__((ext_vector_type(2)));

__device__ __forceinline__ h2 pkh(float a, float b) {
#if __has_builtin(__builtin_amdgcn_cvt_pkrtz)
    return __builtin_amdgcn_cvt_pkrtz(a, b);
#else
    h2 r; r.x = (__fp16)a; r.y = (__fp16)b; return r;
#endif
}

__device__ __forceinline__ float fexp2(float x) {
#if __has_builtin(__builtin_amdgcn_exp2f)
    return __builtin_amdgcn_exp2f(x);
#else
    return exp2f(x);
#endif
}

__device__ __forceinline__ int h2bits(h2 v) { return __builtin_bit_cast(int, v); }

__device__ __forceinline__ h8 pk8(float4 a, float4 b) {
    i4v f;
    f.x = h2bits(pkh(a.x, a.y)); f.y = h2bits(pkh(a.z, a.w));
    f.z = h2bits(pkh(b.x, b.y)); f.w = h2bits(pkh(b.z, b.w));
    return __builtin_bit_cast(h8, f);
}

// S (QK^T C-layout) -> exp -> two B-operand P fragments (verified R7-R17).
// Cross-half exchange via v_permlane32_swap (VALU, no DS latency).
__device__ __forceinline__ void makeP(const fx16& S, bool last, int thr, int hi, h8* P) {
    float pe[16];
    #pragma unroll
    for (int r = 0; r < 16; r++) {
        const int ko = (r & 3) + 8 * (r >> 2);
        float sv = S[r];
        if (last) sv = (ko <= thr) ? sv : -INFINITY;
        pe[r] = fexp2(sv);
    }
    int Hh[8];
    #pragma unroll
    for (int i = 0; i < 8; i++) Hh[i] = h2bits(pkh(pe[2*i], pe[2*i+1]));
#if __has_builtin(__builtin_amdgcn_permlane32_swap)
    #pragma unroll
    for (int s = 0; s < 2; s++) {
        const int b0 = 4 * s;
        auto ra = __builtin_amdgcn_permlane32_swap(Hh[b0+0], Hh[b0+2], false, false);
        auto rb = __builtin_amdgcn_permlane32_swap(Hh[b0+1], Hh[b0+3], false, false);
        i2v pa = __builtin_bit_cast(i2v, ra);
        i2v pb = __builtin_bit_cast(i2v, rb);
        i4v f;
        f.x = pa.x; f.y = pb.x; f.z = pa.y; f.w = pb.y;
        P[s] = __builtin_bit_cast(h8, f);
    }
#else
    #pragma unroll
    for (int s = 0; s < 2; s++) {
        const int b0 = 4 * s;
        int own0 = hi ? Hh[b0+2] : Hh[b0+0];
        int own1 = hi ? Hh[b0+3] : Hh[b0+1];
        int snd0 = hi ? Hh[b0+0] : Hh[b0+2];
        int snd1 = hi ? Hh[b0+1] : Hh[b0+3];
        int rcv0 = __shfl_xor(snd0, 32);
        int rcv1 = __shfl_xor(snd1, 32);
        i4v f;
        f.x = hi ? rcv0 : own0;
        f.y = hi ? rcv1 : own1;
        f.z = hi ? own0 : rcv0;
        f.w = hi ? own1 : rcv1;
        P[s] = __builtin_bit_cast(h8, f);
    }
#endif
}

// ---------------- Kernel 1: QKV projection via MFMA (R21) ----------------
// y = x·W^T as D = A·B with A = W (rows=dd, k=c), B = x^T (k=c, cols=t):
// D cols = t (lane&31), rows = dd per m74 layout. 2 MFMAs replace 8192
// lane-FMAs + 768 scalar W-fetches of the VALU version. Wave = (32-row
// tile, matrix m). Q/K epilogue: permlane32_swap assembles [t][d0..7] h8
// (lo lanes store heads 0-1, hi heads 2-3). V^T native (lane=t, reg=dd).
__global__ __launch_bounds__(192, 3) void qkv_kernel(
    const float* __restrict__ x,
    const float* __restrict__ Wq, const float* __restrict__ bq,
    const float* __restrict__ Wk, const float* __restrict__ bk,
    const float* __restrict__ Wv, const float* __restrict__ bv,
    __fp16* __restrict__ Qo, __fp16* __restrict__ Ko, __fp16* __restrict__ Vo)
{
    const int tid  = threadIdx.x;
    const int m    = tid >> 6;              // wave: 0=Q, 1=K, 2=V
    const int lane = tid & 63;
    const int qc   = lane & 31;
    const int hi   = lane >> 5;

    const int row = blockIdx.x * 32 + qc;   // this lane's token (D column)
    const int b   = row >> 11, t = row & 2047;

    const float* W    = (m == 0) ? Wq : (m == 1) ? Wk : Wv;
    const float* bias = (m == 0) ? bq : (m == 1) ? bk : bv;

    // B operand: x^T.  lane: col = qc, k = c0 + 8*hi + j
    const float* xr = x + (size_t)row * CC + 8 * hi;
    h8 B0 = pk8(*(const float4*)(xr),      *(const float4*)(xr + 4));
    h8 B1 = pk8(*(const float4*)(xr + 16), *(const float4*)(xr + 20));

    // A operand: W.    lane: row = dd = qc, k = c0 + 8*hi + j
    const float* wr = W + (size_t)qc * CC + 8 * hi;
    h8 A0 = pk8(*(const float4*)(wr),      *(const float4*)(wr + 4));
    h8 A1 = pk8(*(const float4*)(wr + 16), *(const float4*)(wr + 20));

    fx16 zc;
    #pragma unroll
    for (int i = 0; i < 16; i++) zc[i] = 0.0f;
    fx16 D = __builtin_amdgcn_mfma_f32_32x32x16_f16(A0, B0, zc, 0, 0, 0);
    D = __builtin_amdgcn_mfma_f32_32x32x16_f16(A1, B1, D, 0, 0, 0);

    // bias: o[r] covers dd = (r&3) + 8*(r>>2) + 4*hi
    float o[16];
    {
        float4 bb0 = *(const float4*)(bias + 0  + 4 * hi);
        float4 bb1 = *(const float4*)(bias + 8  + 4 * hi);
        float4 bb2 = *(const float4*)(bias + 16 + 4 * hi);
        float4 bb3 = *(const float4*)(bias + 24 + 4 * hi);
        const float* bbp[1];
        o[0] = D[0] + bb0.x; o[1] = D[1] + bb0.y; o[2]  = D[2]  + bb0.z; o[3]  = D[3]  + bb0.w;
        o[4] = D[4] + bb1.x; o[5] = D[5] + bb1.y; o[6]  = D[6]  + bb1.z; o[7]  = D[7]  + bb1.w;
        o[8] = D[8] + bb2.x; o[9] = D[9] + bb2.y; o[10] = D[10] + bb2.z; o[11] = D[11] + bb2.w;
        o[12] = D[12] + bb3.x; o[13] = D[13] + bb3.y; o[14] = D[14] + bb3.z; o[15] = D[15] + bb3.w;
        (void)bbp;
    }
    if (m == 0) {   // pre-scale Q by 1/sqrt(D) * log2(e)
        const float qs = 0.3535533905932738f * 1.4426950408889634f;
        #pragma unroll
        for (int r = 0; r < 16; r++) o[r] *= qs;
    }

    if (m == 2) {
        // V^T [bh][d][t] (+ ones row): reg r -> head r>>2, d = (r&3)+4*hi.
        // Fixed (r,hi): consecutive lanes = consecutive t -> coalesced.
        #pragma unroll
        for (int r = 0; r < 16; r++) {
            const int h = r >> 2, d = (r & 3) + 4 * hi;
            Vo[(((size_t)(b * HH + h)) * 9 + d) * TT + t] = (__fp16)o[r];
        }
        const int hA = hi ? 2 : 0, hB = hi ? 3 : 1;
        Vo[(((size_t)(b * HH + hA)) * 9 + 8) * TT + t] = (__fp16)1.0f;
        Vo[(((size_t)(b * HH + hB)) * 9 + 8) * TT + t] = (__fp16)1.0f;
    } else {
        // Q/K rows [bh][t][d0..7]: head g's d0-3 live in lo lane (qc),
        // d4-7 in hi lane (qc+32) -> pair-exchange via permlane32_swap.
        int I0[4], I1[4];
        #pragma unroll
        for (int g = 0; g < 4; g++) {
            I0[g] = h2bits(pkh(o[4*g + 0], o[4*g + 1]));
            I1[g] = h2bits(pkh(o[4*g + 2], o[4*g + 3]));
        }
        i4v fr0, fr1, fr2, fr3;
#if __has_builtin(__builtin_amdgcn_permlane32_swap)
    #define MAKE_FRAG(g, out) { \
        auto ra = __builtin_amdgcn_permlane32_swap(I0[g], I1[g], false, false); \
        auto rb = __builtin_amdgcn_permlane32_swap(I1[g], I0[g], false, false); \
        i2v p1 = __builtin_bit_cast(i2v, ra); \
        i2v p2 = __builtin_bit_cast(i2v, rb); \
        i4v f; \
        f.x = hi ? p2.x : p1.x;  /* d0,d1 */ \
        f.y = hi ? p1.x : p2.x;  /* d2,d3 */ \
        f.z = hi ? p2.y : p1.y;  /* d4,d5 */ \
        f.w = hi ? p1.y : p2.y;  /* d6,d7 */ \
        out = f; }
#else
    #define MAKE_FRAG(g, out) { \
        int s0 = __shfl_xor(I0[g], 32); \
        int s1 = __shfl_xor(I1[g], 32); \
        i4v f; \
        f.x = hi ? s0 : I0[g]; \
        f.y = hi ? s1 : I1[g]; \
        f.z = hi ? I0[g] : s0; \
        f.w = hi ? I1[g] : s1; \
        out = f; }
#endif
        MAKE_FRAG(0, fr0); MAKE_FRAG(1, fr1); MAKE_FRAG(2, fr2); MAKE_FRAG(3, fr3);
    #undef MAKE_FRAG
        i4v fA = hi ? fr2 : fr0;           // lo stores heads 0,1; hi 2,3
        i4v fB = hi ? fr3 : fr1;
        const int gA = hi ? 2 : 0, gB = hi ? 3 : 1;
        __fp16* O = (m == 0) ? Qo : Ko;
        *(i4v*)(O + ((size_t)(b * HH + gA) * TT + t) * DD) = fA;
        *(i4v*)(O + ((size_t)(b * HH + gB) * TT + t) * DD) = fB;
    }
}

// ---------------- Kernel 2: fused attention + projection (R17, best) ---------
// Block 256 thr = 4 waves = 4 heads; each wave owns antithetic qgroup pair
// {ip, 63-ip} = exactly 65 tiles/wave. Wave-private staging, register
// prefetch, no K-loop barriers. makeP via permlane32_swap.
__global__ __launch_bounds__(256, 2) void attn_kernel(
    const __fp16* __restrict__ Qg, const __fp16* __restrict__ Kg,
    const __fp16* __restrict__ Vg,
    const float* __restrict__ Wp, const float* __restrict__ bp,
    float* __restrict__ out)
{
    __shared__ __align__(16) __fp16 KsS[4 * KBS];
    __shared__ __align__(16) __fp16 VtS[4 * VBS];
    __shared__ float zbuf[64 * ZP];

    const int tid  = threadIdx.x;
    const int b    = blockIdx.x & 15;
    const int ip   = blockIdx.x >> 4;       // pair index 0..31
    const int h    = tid >> 6;              // wave = head
    const int lane = tid & 63;
    const int qc   = lane & 31;
    const int hi   = lane >> 5;

    const int bh  = b * HH + h;
    const int qb1 = 32 * ip;                // light qgroup base
    const int qb2 = 32 * (63 - ip);         // heavy qgroup base
    const int keys_needed = qb2 + 32;
    const int nst = (keys_needed + 255) >> 8;

    h8 qf1, qf2;
    {   // B operands: Q^T (pre-scaled); hi half zero (annihilates A garbage)
        h8 qz;
        #pragma unroll
        for (int i = 0; i < 8; i++) qz[i] = (__fp16)0.0f;
        h8 qa = *(const h8*)(Qg + ((size_t)bh * TT + qb1 + qc) * DD);
        h8 qb = *(const h8*)(Qg + ((size_t)bh * TT + qb2 + qc) * DD);
        qf1 = hi ? qz : qa;
        qf2 = hi ? qz : qb;
    }

    fx16 O1, O2, zc;
    #pragma unroll
    for (int i = 0; i < 16; i++) { O1[i] = 0.0f; O2[i] = 0.0f; zc[i] = 0.0f; }

    const int vrow = (qc < 9) ? qc : 8;     // rows>=9 -> ones row (l trick)
    const int thr  = qc - 4 * hi;

    const __fp16* kgl = Kg + (size_t)bh * TT * DD;
    const __fp16* vgl = Vg + (size_t)bh * 9 * TT;
    __fp16* kld = KsS + h * KBS;            // wave-private
    __fp16* vld = VtS + h * VBS;
    const __fp16* kb = kld + qc * DD;
    const __fp16* vb = vld + vrow * VRS + 8 * hi;

    i4v kpre[4], vpre[5];
    {   // prefetch super-tile 0
        const i4v* ks = (const i4v*)kgl;
        #pragma unroll
        for (int r = 0; r < 4; r++) kpre[r] = ks[lane + 64 * r];
        #pragma unroll
        for (int r = 0; r < 5; r++) {
            int i = lane + 64 * r; if (i > 287) i = 287;
            vpre[r] = *(const i4v*)(vgl + (i >> 5) * TT + (i & 31) * 8);
        }
    }

    for (int sti = 0; sti < nst; sti++) {
        const int st = sti * 256;
        {   // commit prefetched tile to wave-private LDS
            i4v* kd = (i4v*)kld;
            #pragma unroll
            for (int r = 0; r < 4; r++) kd[lane + 64 * r] = kpre[r];
            #pragma unroll
            for (int r = 0; r < 5; r++) {
                const int i = lane + 64 * r;
                if (i < 288) *(i4v*)(vld + (i >> 5) * VRS + (i & 31) * 8) = vpre[r];
            }
        }
        if (sti + 1 < nst) {   // issue next tile's global loads (overlap compute)
            const int st2 = st + 256;
            const i4v* ks = (const i4v*)(kgl + (size_t)st2 * DD);
            #pragma unroll
            for (int r = 0; r < 4; r++) kpre[r] = ks[lane + 64 * r];
            #pragma unroll
            for (int r = 0; r < 5; r++) {
                int i = lane + 64 * r; if (i > 287) i = 287;
                vpre[r] = *(const i4v*)(vgl + (i >> 5) * TT + st2 + (i & 31) * 8);
            }
        }

        const int kend = min(st + 256, keys_needed);
        for (int kt = st; kt < kend; kt += 32) {
            const bool a1 = (kt <= qb1);            // wave-uniform
            h8 kf = *(const h8*)(kb + (kt - st) * DD);

            h8 P1[2], P2[2];
            if (a1) {
                fx16 S = __builtin_amdgcn_mfma_f32_32x32x16_f16(kf, qf1, zc, 0, 0, 0);
                makeP(S, kt == qb1, thr, hi, P1);
            }
            {
                fx16 S = __builtin_amdgcn_mfma_f32_32x32x16_f16(kf, qf2, zc, 0, 0, 0);
                makeP(S, kt == qb2, thr, hi, P2);
            }
            #pragma unroll
            for (int s = 0; s < 2; s++) {
                h8 vf = *(const h8*)(vb + (kt - st) + 16 * s);
                if (a1) O1 = __builtin_amdgcn_mfma_f32_32x32x16_f16(vf, P1[s], O1, 0, 0, 0);
                O2 = __builtin_amdgcn_mfma_f32_32x32x16_f16(vf, P2[s], O2, 0, 0, 0);
            }
        }
    }

    {   // z -> LDS: O[4] = l (ones-row); regs 0-3 = d0-3 (hi=0) / d4-7 (hi=1)
        const float i1 = 1.0f / O1[4], i2 = 1.0f / O2[4];
        float* z1 = &zbuf[qc * ZP + h * DD + 4 * hi];
        float* z2 = &zbuf[(32 + qc) * ZP + h * DD + 4 * hi];
        z1[0] = O1[0]*i1; z1[1] = O1[1]*i1; z1[2] = O1[2]*i1; z1[3] = O1[3]*i1;
        z2[0] = O2[0]*i2; z2[1] = O2[1]*i2; z2[2] = O2[2]*i2; z2[3] = O2[3]*i2;
    }
    __syncthreads();

    {   // in-block projection: wave = 8-col output segment (uniform Wp -> s_loads)
        const int seg = tid >> 6;
        const int r = tid & 63;             // rows 0-31 -> qg ip, 32-63 -> qg 63-ip
        float zr[CC];
        #pragma unroll
        for (int c = 0; c < CC; c++) zr[c] = zbuf[r * ZP + c];
        float o[DD];
        #pragma unroll
        for (int d = 0; d < DD; d++) {
            const int dd = seg * DD + d;
            float acc = bp[dd];
            #pragma unroll
            for (int c = 0; c < CC; c++) acc += zr[c] * Wp[dd * CC + c];
            o[d] = acc;
        }
        const int qglob = (r < 32) ? (ip * 32 + r) : ((63 - ip) * 32 + (r - 32));
        float* dst = out + ((size_t)b * TT + qglob) * CC + seg * DD;
        ((float4*)dst)[0] = make_float4(o[0], o[1], o[2], o[3]);
        ((float4*)dst)[1] = make_float4(o[4], o[5], o[6], o[7]);
    }
}

extern "C" void kernel_launch(void* const* d_in, const int* in_sizes, int n_in,
                              void* d_out, int out_size, void* d_ws, size_t ws_size,
                              hipStream_t stream) {
    const float* x  = (const float*)d_in[0];
    const float* Wq = (const float*)d_in[1];
    const float* bq = (const float*)d_in[2];
    const float* Wk = (const float*)d_in[3];
    const float* bk = (const float*)d_in[4];
    const float* Wv = (const float*)d_in[5];
    const float* bv = (const float*)d_in[6];
    const float* Wp = (const float*)d_in[7];
    const float* bp = (const float*)d_in[8];
    float* out = (float*)d_out;

    const size_t NE = (size_t)BB * HH * TT * DD;   // 1M
    __fp16* Qh = (__fp16*)d_ws;                    // 2 MB (pre-scaled)
    __fp16* Kh = Qh + NE;                          // 2 MB
    __fp16* Vt = Kh + NE;                          // 2.25 MB  [bh][9][T]

    qkv_kernel<<<dim3(BB * TT / 32), 192, 0, stream>>>(x, Wq, bq, Wk, bk, Wv, bv, Qh, Kh, Vt);
    attn_kernel<<<dim3(BB * 32), 256, 0, stream>>>(Qh, Kh, Vt, Wp, bp, out);
}